// Round 15
// baseline (528.121 us; speedup 1.0000x reference)
//
#include <hip/hip_runtime.h>

#define N_NODES 50000
#define N_ENT   100000
#define N_REL   16
#define DIM     128
#define E_EDGES 600000
#define NQ      8192
#define PATH_DIM 5
#define NK      (N_NODES * N_REL)        /* 800000 (rel,dst) segments, rel-major */
#define NBLK_SEG (NK / 256)              /* 3125 */
#define KTOT    (N_REL * DIM + DIM)      /* 2176 */
#define NG      (KTOT / 32)              /* 68 */
#define BM      64                       /* rows per block (2 row-groups x 32) */
#define EB      ((E_EDGES + 255) / 256)
#define H0B     ((N_NODES * 32) / 256)
#define WCB     ((2 * NG * 8 * 512) / 256)

typedef __attribute__((ext_vector_type(8))) short short8;
typedef __attribute__((ext_vector_type(4))) float floatx4;
typedef __attribute__((ext_vector_type(4))) unsigned uintx4;

static __device__ __forceinline__ short f2bf(float x) {
  unsigned u = __builtin_bit_cast(unsigned, x);
  u = (u + 0x7FFFu + ((u >> 16) & 1u)) >> 16;   // RNE
  return (short)u;
}
static __device__ __forceinline__ float bf_lo(unsigned u) {
  return __builtin_bit_cast(float, u << 16);
}
static __device__ __forceinline__ float bf_hi(unsigned u) {
  return __builtin_bit_cast(float, u & 0xffff0000u);
}
static __device__ __forceinline__ unsigned pk2(float a, float b) {
  return (unsigned)(unsigned short)f2bf(a) | ((unsigned)(unsigned short)f2bf(b) << 16);
}

static __device__ __forceinline__ int wave_incl_scan(int x) {
  int lane = threadIdx.x & 63;
  #pragma unroll
  for (int off = 1; off < 64; off <<= 1) {
    int y = __shfl_up(x, off, 64);
    if (lane >= off) x += y;
  }
  return x;
}

// ---------- fused prep: edge hist | h0 gather | weight tiles ----------
__global__ void k_prep(const int* __restrict__ ei, const int* __restrict__ et,
                       int* __restrict__ hist,
                       const int* __restrict__ nid, const float* __restrict__ emb,
                       unsigned* __restrict__ h,
                       const float* __restrict__ wrel, const float* __restrict__ wself,
                       short* __restrict__ wt) {
  int b = blockIdx.x, t = threadIdx.x;
  if (b < EB) {
    int e = b * 256 + t;
    if (e < E_EDGES) {
      int key = et[e] * N_NODES + ei[E_EDGES + e];
      atomicAdd(&hist[key], 1);
    }
  } else if (b < EB + H0B) {
    int g = (b - EB) * 256 + t;                    // over N*32
    int n = g >> 5, q = g & 31;
    float4 v = *(const float4*)(emb + (size_t)nid[n] * DIM + q * 4);
    uint2 pk;
    pk.x = pk2(v.x, v.y);
    pk.y = pk2(v.z, v.w);
    *(uint2*)(h + (size_t)n * 64 + q * 2) = pk;
  } else {
    // wt layout: [l][g=k/32][nt8=n/16] tile [16 rA][32 q] shorts (1KB).
    // Lane varies rA (=n) fastest -> coalesced wrel/wself reads.
    int idx = (b - EB - H0B) * 256 + t;
    int u = idx & 511;
    int tile = idx >> 9;
    int rA = u & 15, q = u >> 4;
    int nt8 = tile & 7;
    int lg = tile >> 3;
    int l = lg / NG, g = lg % NG;
    int n = nt8 * 16 + rA;
    int k = g * 32 + q;
    float v;
    if (k < N_REL * DIM) {
      int r = k >> 7, d = k & 127;
      v = wrel[(((size_t)l * N_REL + r) * DIM + d) * DIM + n];
    } else {
      int d = k - N_REL * DIM;
      v = wself[((size_t)l * DIM + d) * DIM + n];
    }
    wt[(size_t)tile * 512 + rA * 32 + q] = f2bf(v);
  }
}

__global__ void k_bsum(const int* __restrict__ hist, int* __restrict__ bsum) {
  int t = threadIdx.x;
  int v = hist[blockIdx.x * 256 + t];
  #pragma unroll
  for (int off = 32; off; off >>= 1) v += __shfl_xor(v, off, 64);
  __shared__ int s4[4];
  if ((t & 63) == 0) s4[t >> 6] = v;
  __syncthreads();
  if (t == 0) bsum[blockIdx.x] = s4[0] + s4[1] + s4[2] + s4[3];
}

// k_offsets computes its own block prefix over bsum (no separate scan kernel)
__global__ void k_offsets(const int* __restrict__ hist, const int* __restrict__ bsum,
                          int* __restrict__ offs, int* __restrict__ cursor) {
  int t = threadIdx.x;
  int b = blockIdx.x;
  int g = b * 256 + t;
  int part = 0;
  for (int i = t; i < b; i += 256) part += bsum[i];
  #pragma unroll
  for (int off = 32; off; off >>= 1) part += __shfl_xor(part, off, 64);
  __shared__ int pre4[4];
  int wid = t >> 6, lane = t & 63;
  if (lane == 0) pre4[wid] = part;
  __syncthreads();
  int blockpre = pre4[0] + pre4[1] + pre4[2] + pre4[3];

  int v = hist[g];
  int incl = wave_incl_scan(v);
  __shared__ int wsum[4];
  if (lane == 63) wsum[wid] = incl;
  __syncthreads();
  int wexcl = 0;
  for (int i = 0; i < wid; i++) wexcl += wsum[i];
  int off = blockpre + wexcl + incl - v;
  offs[g] = off;
  cursor[g] = off;
  if (g == NK - 1) offs[NK] = off + v;
}

__global__ void k_scatter(const int* __restrict__ ei, const int* __restrict__ et,
                          int* __restrict__ cursor, int* __restrict__ ssrc) {
  int e = blockIdx.x * 256 + threadIdx.x;
  if (e >= E_EDGES) return;
  int src = ei[e];
  int key = et[e] * N_NODES + ei[E_EDGES + e];
  int pos = atomicAdd(&cursor[key], 1);
  ssrc[pos] = src;
}

// ---------- fused layer: 32 rows/wave, register B-reuse x2, K-split ----------
// 4 waves = 2 row-groups(rg) x 2 K-groups(kg). Wave owns 32 rows (2 A-groups of
// 16) and 8 relations. Gather = round-11's verified per-lane loop, run per
// A-group; then ONE B-loop reads each fragment once and feeds 2 MFMAs
// (halves B instruction count + L1 B-traffic vs all prior rounds).
__global__ __launch_bounds__(256, 2)
void k_layer(const unsigned* __restrict__ hin, const int* __restrict__ offs,
             const int* __restrict__ ssrc, const short* __restrict__ wt,
             unsigned* __restrict__ hout) {
  __shared__ int offsS[16][68];        // 16 rels x 65 boundaries (rows row0..row0+64)
  __shared__ float cred[2][2][32][64]; // [rg][g][nt*4+j][lane] f32 partials, 32 KB
  int t = threadIdx.x;
  int w = t >> 6, lane = t & 63;
  int quad = lane >> 4, rA = lane & 15;
  int kg = w & 1, rg = w >> 1;
  int row0 = blockIdx.x * BM;
  int rbase = row0 + rg * 32;
  int rb32 = rg * 32;

  for (int idx = t; idx < 16 * 80; idx += 256) {
    int r = idx / 80, j = idx - r * 80;
    if (j < 65) offsS[r][j] = offs[min(r * N_NODES + row0 + j, NK)];
  }
  __syncthreads();

  floatx4 acc[2][8];                   // [g][nt]
  #pragma unroll
  for (int g = 0; g < 2; ++g)
    #pragma unroll
    for (int nt = 0; nt < 8; ++nt) acc[g][nt] = (floatx4)0.f;

  const short* hb = (const short*)hin;

  int rlo = kg * 8, rhi = rlo + 8;
  for (int r = rlo; r < rhi; ++r) {
    short8 af[2][4];
    #pragma unroll
    for (int g = 0; g < 2; ++g) {
      int o = offsS[r][rb32 + g * 16 + rA];
      int c = offsS[r][rb32 + g * 16 + rA + 1] - o;   // lane-local count
      int mc = c;
      #pragma unroll
      for (int sh = 32; sh; sh >>= 1) mc = max(mc, __shfl_xor(mc, sh, 64));
      float s[4][8];
      #pragma unroll
      for (int ks = 0; ks < 4; ++ks)
        #pragma unroll
        for (int m = 0; m < 8; ++m) s[ks][m] = 0.f;
      int eid = (c > 0) ? ssrc[o] : 0;
      for (int i = 0; i < mc; ++i) {        // wave-uniform trip count
        int eidn = (i + 1 < c) ? ssrc[o + i + 1] : 0;   // prefetch next id
        if (i < c) {
          const short* hp = hb + (size_t)eid * DIM + quad * 8;
          #pragma unroll
          for (int ks = 0; ks < 4; ++ks) {  // 4 x 16B; quads cover 256B row
            uint4 d = *(const uint4*)(hp + ks * 32);
            s[ks][0] += bf_lo(d.x); s[ks][1] += bf_hi(d.x);
            s[ks][2] += bf_lo(d.y); s[ks][3] += bf_hi(d.y);
            s[ks][4] += bf_lo(d.z); s[ks][5] += bf_hi(d.z);
            s[ks][6] += bf_lo(d.w); s[ks][7] += bf_hi(d.w);
          }
        }
        eid = eidn;
      }
      float inv = 1.0f / (float)(c > 0 ? c : 1);  // lane-local
      #pragma unroll
      for (int ks = 0; ks < 4; ++ks) {
        uintx4 ap;
        #pragma unroll
        for (int m = 0; m < 4; ++m) {
          float a = s[ks][2 * m] * inv, b = s[ks][2 * m + 1] * inv;
          unsigned pk;
          asm("v_cvt_pk_bf16_f32 %0, %1, %2" : "=v"(pk) : "v"(a), "v"(b));  // RNE
          ap[m] = pk;
        }
        af[g][ks] = __builtin_bit_cast(short8, ap);
      }
    }
    // B-loop: each fragment read ONCE, feeds both row-groups
    #pragma unroll
    for (int ks = 0; ks < 4; ++ks) {
      const short* bp = wt + (size_t)((r * 4 + ks) * 8) * 512 + rA * 32 + quad * 8;
      #pragma unroll
      for (int nt = 0; nt < 8; ++nt) {
        short8 b = *(const short8*)(bp + nt * 512);   // 1KB tile, L2-hot
        acc[0][nt] = __builtin_amdgcn_mfma_f32_16x16x32_bf16(af[0][ks], b, acc[0][nt], 0, 0, 0);
        acc[1][nt] = __builtin_amdgcn_mfma_f32_16x16x32_bf16(af[1][ks], b, acc[1][nt], 0, 0, 0);
      }
    }
  }

  if (kg == 1) {
    // self slot for both row-groups, B read once
    short8 af[2][4];
    #pragma unroll
    for (int g = 0; g < 2; ++g) {
      int lr = min(rbase + g * 16 + rA, N_NODES - 1);
      const short* hp = hb + (size_t)lr * DIM + quad * 8;
      #pragma unroll
      for (int ks = 0; ks < 4; ++ks) af[g][ks] = *(const short8*)(hp + ks * 32);
    }
    #pragma unroll
    for (int ks = 0; ks < 4; ++ks) {
      const short* bp = wt + (size_t)((16 * 4 + ks) * 8) * 512 + rA * 32 + quad * 8;
      #pragma unroll
      for (int nt = 0; nt < 8; ++nt) {
        short8 b = *(const short8*)(bp + nt * 512);
        acc[0][nt] = __builtin_amdgcn_mfma_f32_16x16x32_bf16(af[0][ks], b, acc[0][nt], 0, 0, 0);
        acc[1][nt] = __builtin_amdgcn_mfma_f32_16x16x32_bf16(af[1][ks], b, acc[1][nt], 0, 0, 0);
      }
    }
    // dump f32 partials (conflict-free: bank = lane%32)
    #pragma unroll
    for (int g = 0; g < 2; ++g)
      #pragma unroll
      for (int nt = 0; nt < 8; ++nt)
        #pragma unroll
        for (int j = 0; j < 4; ++j)
          cred[rg][g][nt * 4 + j][lane] = acc[g][nt][j];
  }
  __syncthreads();
  if (kg == 0) {
    // combine + relu + store. C layout: row=quad*4+j, col=nt*16+rA
    #pragma unroll
    for (int g = 0; g < 2; ++g)
      #pragma unroll
      for (int nt = 0; nt < 8; ++nt)
        #pragma unroll
        for (int j = 0; j < 4; ++j) {
          float v = acc[g][nt][j] + cred[rg][g][nt * 4 + j][lane];
          int row = rbase + g * 16 + quad * 4 + j;
          int col = nt * 16 + rA;
          if (row < N_NODES)
            ((short*)hout)[(size_t)row * DIM + col] = f2bf(fmaxf(v, 0.f));
        }
  }
}

// ---------- scoring (bf16 h) ----------
__global__ void k_score(const unsigned* __restrict__ h, const int* __restrict__ heads,
                        const int* __restrict__ rels, const int* __restrict__ tails,
                        const float* __restrict__ rel_emb, const float* __restrict__ path_feat,
                        const int* __restrict__ task_idx, const float* __restrict__ delta_w,
                        const float* __restrict__ lambda_logit, const float* __restrict__ rule_init,
                        float* __restrict__ out) {
  int q = (blockIdx.x * 256 + threadIdx.x) >> 6;
  int lane = threadIdx.x & 63;
  int hd = heads[q], tl = tails[q], rl = rels[q];
  unsigned ua = h[(size_t)hd * 64 + lane];
  unsigned uc = h[(size_t)tl * 64 + lane];
  float2 r = *(const float2*)(rel_emb + (size_t)rl * DIM + lane * 2);
  float s = bf_lo(ua) * r.x * bf_lo(uc) + bf_hi(ua) * r.y * bf_hi(uc);
  #pragma unroll
  for (int off = 32; off; off >>= 1) s += __shfl_xor(s, off, 64);
  if (lane == 0) {
    int task = task_idx[0];
    float sp = 0.f;
    #pragma unroll
    for (int p = 0; p < PATH_DIM; p++)
      sp += path_feat[q * PATH_DIM + p] *
            (rule_init[task * PATH_DIM + p] + delta_w[task * PATH_DIM + p]);
    float lam = 1.f / (1.f + __expf(-lambda_logit[task]));
    out[q] = lam * s + (1.f - lam) * sp;
  }
}

extern "C" void kernel_launch(void* const* d_in, const int* in_sizes, int n_in,
                              void* d_out, int out_size, void* d_ws, size_t ws_size,
                              hipStream_t stream) {
  const int*   node_ids   = (const int*)d_in[0];
  const int*   edge_index = (const int*)d_in[1];
  const int*   edge_type  = (const int*)d_in[2];
  const int*   heads      = (const int*)d_in[3];
  const int*   rels       = (const int*)d_in[4];
  const int*   tails      = (const int*)d_in[5];
  const float* path_feat  = (const float*)d_in[6];
  const int*   task_idx   = (const int*)d_in[7];
  const float* entity_emb = (const float*)d_in[8];
  const float* rel_emb    = (const float*)d_in[9];
  const float* W_self     = (const float*)d_in[10];
  const float* W_rel      = (const float*)d_in[11];
  const float* delta_w    = (const float*)d_in[12];
  const float* lambda_lg  = (const float*)d_in[13];
  const float* rule_init  = (const float*)d_in[14];

  char* ws = (char*)d_ws;
  size_t off = 0;
  auto alloc = [&](size_t bytes) -> void* {
    void* p = ws + off;
    off = (off + bytes + 255) & ~(size_t)255;
    return p;
  };
  unsigned* h_a    = (unsigned*)alloc((size_t)N_NODES * DIM * 2);
  unsigned* h_b    = (unsigned*)alloc((size_t)N_NODES * DIM * 2);
  short*    wt     = (short*)alloc((size_t)2 * NG * 8 * 512 * 2);
  int*      offs   = (int*)alloc((size_t)(NK + 1) * 4);
  int*      ssrc   = (int*)alloc((size_t)E_EDGES * 4);
  int*      hist   = (int*)alloc((size_t)(NK + 1) * 4);
  int*      cursor = (int*)alloc((size_t)NK * 4);
  int*      bsum   = (int*)alloc((size_t)NBLK_SEG * 4);

  hipMemsetAsync(hist, 0, (size_t)(NK + 1) * 4, stream);
  k_prep<<<EB + H0B + WCB, 256, 0, stream>>>(edge_index, edge_type, hist,
                                             node_ids, entity_emb, h_a,
                                             W_rel, W_self, wt);
  k_bsum<<<NBLK_SEG, 256, 0, stream>>>(hist, bsum);
  k_offsets<<<NBLK_SEG, 256, 0, stream>>>(hist, bsum, offs, cursor);
  k_scatter<<<EB, 256, 0, stream>>>(edge_index, edge_type, cursor, ssrc);

  const unsigned* hin = h_a;
  unsigned* hout = h_b;
  int nblk = (N_NODES + BM - 1) / BM;
  for (int l = 0; l < 2; l++) {
    k_layer<<<nblk, 256, 0, stream>>>(hin, offs, ssrc,
                                      wt + (size_t)l * NG * 8 * 512, hout);
    const unsigned* tmp = hout;
    hout = (unsigned*)hin;
    hin = tmp;
  }
  k_score<<<NQ / 4, 256, 0, stream>>>(hin, heads, rels, tails, rel_emb, path_feat,
                                      task_idx, delta_w, lambda_lg, rule_init,
                                      (float*)d_out);
}

// Round 16
// 438.248 us; speedup vs baseline: 1.2051x; 1.2051x over previous
//
#include <hip/hip_runtime.h>

#define N_NODES 50000
#define N_ENT   100000
#define N_REL   16
#define DIM     128
#define E_EDGES 600000
#define NQ      8192
#define PATH_DIM 5
#define NK      (N_NODES * N_REL)        /* 800000 (rel,dst) segments, rel-major */
#define NBLK_SEG (NK / 256)              /* 3125 */
#define KTOT    (N_REL * DIM + DIM)      /* 2176 */
#define NG      (KTOT / 32)              /* 68 */
#define BM      64                       /* rows per block */
#define EB      ((E_EDGES + 255) / 256)  /* 2344 */
#define H0B     ((N_NODES * 32) / 256)   /* 6250 */
#define WCB     ((2 * NG * 8 * 512) / 256) /* 2176 */

typedef __attribute__((ext_vector_type(8))) short short8;
typedef __attribute__((ext_vector_type(4))) float floatx4;

static __device__ __forceinline__ short f2bf(float x) {
  unsigned u = __builtin_bit_cast(unsigned, x);
  u = (u + 0x7FFFu + ((u >> 16) & 1u)) >> 16;   // RNE
  return (short)u;
}
static __device__ __forceinline__ float bf_lo(unsigned u) {
  return __builtin_bit_cast(float, u << 16);
}
static __device__ __forceinline__ float bf_hi(unsigned u) {
  return __builtin_bit_cast(float, u & 0xffff0000u);
}
static __device__ __forceinline__ unsigned pk2(float a, float b) {
  return (unsigned)(unsigned short)f2bf(a) | ((unsigned)(unsigned short)f2bf(b) << 16);
}

static __device__ __forceinline__ int wave_incl_scan(int x) {
  int lane = threadIdx.x & 63;
  #pragma unroll
  for (int off = 1; off < 64; off <<= 1) {
    int y = __shfl_up(x, off, 64);
    if (lane >= off) x += y;
  }
  return x;
}

// counted-vmcnt primitives (round-9 verified): asm volatile pins program order;
// saddr form keeps address math scalar (SGPR base + shared VGPR byte offset).
static __device__ __forceinline__ unsigned gload_su(const unsigned* base, unsigned voff) {
  unsigned r;
  asm volatile("global_load_dword %0, %1, %2" : "=v"(r) : "v"(voff), "s"(base) : "memory");
  return r;
}
#define WAIT_VM(N) do { asm volatile("s_waitcnt vmcnt(" #N ")" ::: "memory"); \
                        __builtin_amdgcn_sched_barrier(0); } while (0)
// raw barrier: does NOT drain vmcnt (round-8 lesson). LDS visibility via lgkmcnt.
#define BAR_LDS() do { asm volatile("s_waitcnt lgkmcnt(0)" ::: "memory"); \
                       __builtin_amdgcn_s_barrier(); \
                       asm volatile("" ::: "memory"); } while (0)

// ---------- fused prep: edge hist | h0 gather | weight tiles ----------
__global__ void k_prep(const int* __restrict__ ei, const int* __restrict__ et,
                       int* __restrict__ hist,
                       const int* __restrict__ nid, const float* __restrict__ emb,
                       unsigned* __restrict__ h,
                       const float* __restrict__ wrel, const float* __restrict__ wself,
                       short* __restrict__ wt) {
  int b = blockIdx.x, t = threadIdx.x;
  if (b < EB) {
    int e = b * 256 + t;
    if (e < E_EDGES) {
      int key = et[e] * N_NODES + ei[E_EDGES + e];
      atomicAdd(&hist[key], 1);
    }
  } else if (b < EB + H0B) {
    int g = (b - EB) * 256 + t;                    // over N*32
    int n = g >> 5, q = g & 31;
    float4 v = *(const float4*)(emb + (size_t)nid[n] * DIM + q * 4);
    uint2 pk;
    pk.x = pk2(v.x, v.y);
    pk.y = pk2(v.z, v.w);
    *(uint2*)(h + (size_t)n * 64 + q * 2) = pk;
  } else {
    // wt layout: [l][g=k/32][nt8=n/16] tile [16 rA][32 q] shorts (1KB).
    // Lane varies rA (=n) fastest -> coalesced wrel/wself reads (round-14 verified).
    int idx = (b - EB - H0B) * 256 + t;
    int u = idx & 511;
    int tile = idx >> 9;
    int rA = u & 15, q = u >> 4;
    int nt8 = tile & 7;
    int lg = tile >> 3;
    int l = lg / NG, g = lg % NG;
    int n = nt8 * 16 + rA;
    int k = g * 32 + q;
    float v;
    if (k < N_REL * DIM) {
      int r = k >> 7, d = k & 127;
      v = wrel[(((size_t)l * N_REL + r) * DIM + d) * DIM + n];
    } else {
      int d = k - N_REL * DIM;
      v = wself[((size_t)l * DIM + d) * DIM + n];
    }
    wt[(size_t)tile * 512 + rA * 32 + q] = f2bf(v);
  }
}

__global__ void k_bsum(const int* __restrict__ hist, int* __restrict__ bsum) {
  int t = threadIdx.x;
  int v = hist[blockIdx.x * 256 + t];
  #pragma unroll
  for (int off = 32; off; off >>= 1) v += __shfl_xor(v, off, 64);
  __shared__ int s4[4];
  if ((t & 63) == 0) s4[t >> 6] = v;
  __syncthreads();
  if (t == 0) bsum[blockIdx.x] = s4[0] + s4[1] + s4[2] + s4[3];
}

// k_offsets computes its own block prefix over bsum (round-14 verified; kills
// the serial 1-block k_bscan dispatch). 3125 L2-hot ints, <=13 reads/thread.
__global__ void k_offsets(const int* __restrict__ hist, const int* __restrict__ bsum,
                          int* __restrict__ offs, int* __restrict__ cursor) {
  int t = threadIdx.x;
  int b = blockIdx.x;
  int g = b * 256 + t;
  int part = 0;
  for (int i = t; i < b; i += 256) part += bsum[i];
  #pragma unroll
  for (int off = 32; off; off >>= 1) part += __shfl_xor(part, off, 64);
  __shared__ int pre4[4];
  int wid = t >> 6, lane = t & 63;
  if (lane == 0) pre4[wid] = part;
  __syncthreads();
  int blockpre = pre4[0] + pre4[1] + pre4[2] + pre4[3];

  int v = hist[g];
  int incl = wave_incl_scan(v);
  __shared__ int wsum[4];
  if (lane == 63) wsum[wid] = incl;
  __syncthreads();
  int wexcl = 0;
  for (int i = 0; i < wid; i++) wexcl += wsum[i];
  int off = blockpre + wexcl + incl - v;
  offs[g] = off;
  cursor[g] = off;
  if (g == NK - 1) offs[NK] = off + v;
}

__global__ void k_scatter(const int* __restrict__ ei, const int* __restrict__ et,
                          int* __restrict__ cursor, int* __restrict__ ssrc) {
  int e = blockIdx.x * 256 + threadIdx.x;
  if (e >= E_EDGES) return;
  int src = ei[e];
  int key = et[e] * N_NODES + ei[E_EDGES + e];
  int pos = atomicAdd(&cursor[key], 1);
  ssrc[pos] = src;
}

// ---------- fused layer (round-9 verified, best measured: 134us) ----------
// 4 producer waves (16 segs each) + 4 consumer waves. Raw s_barrier (no vmcnt
// drain) lets the 2-deep counted pipeline span phases:
//   entry: [sjvec(p+2)] + [u(p+1)]x32 = 33 outstanding
//   WAIT(32) -> sjvec(p+2) ready; issue sjvec(p+3), issue u(p+2)x32;
//   WAIT(33) -> u(p+1) ready; accum(rel p+1); lgkm(0); s_barrier.
__global__ __launch_bounds__(512, 4)
void k_layer(const unsigned* __restrict__ hin, const int* __restrict__ offs,
             const int* __restrict__ ssrc, const short* __restrict__ wt,
             unsigned* __restrict__ hout) {
  __shared__ unsigned As[2][BM][68];  // 272B row stride, double-buffered
  __shared__ int offsS[16][66];       // per-rel segment boundaries for block rows
  int t = threadIdx.x;
  int w = t >> 6, lane = t & 63;
  int row0 = blockIdx.x * BM;

  for (int idx = t; idx < 16 * 80; idx += 512) {
    int it = idx / 80, rr = idx - it * 80;
    if (rr < 65) offsS[it][rr] = offs[min(it * N_NODES + row0 + rr, NK)];
  }
  BAR_LDS();                          // barrier #0

  if (w < 4) {
    // ================= producer =================
    int w16 = w * 16;
    unsigned voffl = (unsigned)lane * 4u;   // shared per-lane byte offset
    unsigned uA[32], uB[32];
    int sjA, sjB;

    auto issue_sj = [&](int r) -> int {     // 64 edge ids of this wave's range
      int o0 = offsS[r][w16];
      unsigned vo = (unsigned)min(o0 + lane, E_EDGES - 1) * 4u;
      return (int)gload_su((const unsigned*)ssrc, vo);
    };
    auto issue_u = [&](unsigned (&u)[32], int sjv) {
      #pragma unroll
      for (int e = 0; e < 32; ++e) {
        int sr = __builtin_amdgcn_readlane(sjv, e);   // valid node id always
        u[e] = gload_su(hin + (size_t)sr * 64, voffl);
      }
    };
    auto accum = [&](unsigned (&u)[32], int r) {
      int olv = offsS[r][w16 + min(lane, 16)];
      int o0 = __builtin_amdgcn_readfirstlane(olv);
      int total = __builtin_amdgcn_readlane(olv, 16) - o0;
      int nxt = __shfl(olv, lane + 1);
      int cnl = nxt - olv;                            // lanes 0..15 meaningful
      float ivf = 1.0f / (float)(cnl > 0 ? cnl : 1);  // one div per wave-rel
      int ivb = __builtin_bit_cast(int, ivf);
      int k = 0;
      int nb = __builtin_amdgcn_readlane(olv, 1) - o0;
      float r0 = 0.f, r1 = 0.f;
      int buf = r & 1;
      auto close1 = [&]() {
        float f = __builtin_bit_cast(float, __builtin_amdgcn_readlane(ivb, k));
        float a = r0 * f, b2 = r1 * f;
        unsigned pk;
        asm("v_cvt_pk_bf16_f32 %0, %1, %2" : "=v"(pk) : "v"(a), "v"(b2));  // RNE
        As[buf][w16 + k][lane] = pk;
        r0 = 0.f; r1 = 0.f;
        ++k;
        nb = __builtin_amdgcn_readlane(olv, min(k + 1, 16)) - o0;
      };
      #pragma unroll
      for (int e = 0; e < 32; ++e) {
        while (k < 16 && nb == e) close1();           // segs ending at pos e (incl empties)
        if (e < total) { r0 += bf_lo(u[e]); r1 += bf_hi(u[e]); }
      }
      if (total > 32) {                               // rare serial tail (drains pipe; self-heals)
        for (int e = 32; e < total; ++e) {
          while (k < 16 && nb == e) close1();
          int sr = __builtin_amdgcn_readfirstlane(ssrc[o0 + e]);
          unsigned uu = hin[(size_t)sr * 64 + lane];
          r0 += bf_lo(uu); r1 += bf_hi(uu);
        }
      }
      while (k < 16) close1();                        // segs ending at total + trailing empties
    };

    // ---- prologue ----
    sjA = issue_sj(0);                 // [1]
    WAIT_VM(0);
    sjB = issue_sj(1);                 // [1]
    issue_u(uA, sjA);                  // [33]  rel 0
    WAIT_VM(32);                       // sjB ready; uA in flight
    sjA = issue_sj(2);                 // [33]
    issue_u(uB, sjB);                  // [65]  rel 1
    WAIT_VM(33);                       // uA ready
    accum(uA, 0);
    BAR_LDS();                         // barrier #1: As[0] visible

    // ---- phases p = 0..14 (produce rels 1..15) ----
    auto phase = [&](int p, unsigned (&uI)[32], unsigned (&uAcc)[32],
                     int &sjC, int &sjN) {
      WAIT_VM(32);                     // sjC (rel p+2) ready
      sjN = issue_sj(min(p + 3, 15));  // [33]
      issue_u(uI, sjC);                // [65]  rel p+2 (clamped loads harmless)
      WAIT_VM(33);                     // uAcc (rel p+1) ready
      accum(uAcc, p + 1);
      BAR_LDS();
    };
    for (int p = 0; p < 15; p += 2) {
      phase(p, uA, uB, sjA, sjB);
      if (p + 1 < 15) phase(p + 1, uB, uA, sjB, sjA);
    }

    // ---- self slot into As[0] (consumed at it=16) ----
    #pragma unroll
    for (int j = 0; j < 16; ++j) {
      int lr = min(row0 + w16 + j, N_NODES - 1);
      As[0][w16 + j][lane] = hin[(size_t)lr * 64 + lane];
    }
    BAR_LDS();                         // barrier #17
  } else {
    // ================= consumer =================
    int wid = w - 4, wm = wid >> 1, wn = wid & 1;
    int quad = lane >> 4, rA = lane & 15;
    floatx4 acc[2][4];
    #pragma unroll
    for (int a = 0; a < 2; a++)
      #pragma unroll
      for (int b = 0; b < 4; b++) acc[a][b] = (floatx4)0.f;

    BAR_LDS();                         // barrier #1 (matches producer prologue)
    for (int it = 0; it < 17; ++it) {
      int buf = it & 1;
      const short* arow0 = (const short*)&As[buf][wm * 32 + rA][0];
      const short* arow1 = (const short*)&As[buf][wm * 32 + 16 + rA][0];
      #pragma unroll
      for (int ks = 0; ks < 4; ++ks) {
        short8 a0 = *(const short8*)(arow0 + ks * 32 + quad * 8);
        short8 a1 = *(const short8*)(arow1 + ks * 32 + quad * 8);
        int kg = it * 4 + ks;
        const short* bp = wt + (size_t)(kg * 8 + wn * 4) * 512 + rA * 32 + quad * 8;
        #pragma unroll
        for (int nt = 0; nt < 4; ++nt) {
          short8 b = *(const short8*)(bp + nt * 512);  // 1KB tile, L2-hot
          acc[0][nt] = __builtin_amdgcn_mfma_f32_16x16x32_bf16(a0, b, acc[0][nt], 0, 0, 0);
          acc[1][nt] = __builtin_amdgcn_mfma_f32_16x16x32_bf16(a1, b, acc[1][nt], 0, 0, 0);
        }
      }
      if (it < 16) BAR_LDS();          // barriers #2..#17
    }
    // epilogue: C row=(lane>>4)*4+j, col=lane&15 within each 16x16 tile
    #pragma unroll
    for (int mt = 0; mt < 2; ++mt)
      #pragma unroll
      for (int nt = 0; nt < 4; ++nt)
        #pragma unroll
        for (int j = 0; j < 4; ++j) {
          int row = row0 + wm * 32 + mt * 16 + quad * 4 + j;
          int col = wn * 64 + nt * 16 + rA;
          if (row < N_NODES)
            ((short*)hout)[(size_t)row * DIM + col] = f2bf(fmaxf(acc[mt][nt][j], 0.f));
        }
  }
}

// ---------- scoring (bf16 h) ----------
__global__ void k_score(const unsigned* __restrict__ h, const int* __restrict__ heads,
                        const int* __restrict__ rels, const int* __restrict__ tails,
                        const float* __restrict__ rel_emb, const float* __restrict__ path_feat,
                        const int* __restrict__ task_idx, const float* __restrict__ delta_w,
                        const float* __restrict__ lambda_logit, const float* __restrict__ rule_init,
                        float* __restrict__ out) {
  int q = (blockIdx.x * 256 + threadIdx.x) >> 6;
  int lane = threadIdx.x & 63;
  int hd = heads[q], tl = tails[q], rl = rels[q];
  unsigned ua = h[(size_t)hd * 64 + lane];
  unsigned uc = h[(size_t)tl * 64 + lane];
  float2 r = *(const float2*)(rel_emb + (size_t)rl * DIM + lane * 2);
  float s = bf_lo(ua) * r.x * bf_lo(uc) + bf_hi(ua) * r.y * bf_hi(uc);
  #pragma unroll
  for (int off = 32; off; off >>= 1) s += __shfl_xor(s, off, 64);
  if (lane == 0) {
    int task = task_idx[0];
    float sp = 0.f;
    #pragma unroll
    for (int p = 0; p < PATH_DIM; p++)
      sp += path_feat[q * PATH_DIM + p] *
            (rule_init[task * PATH_DIM + p] + delta_w[task * PATH_DIM + p]);
    float lam = 1.f / (1.f + __expf(-lambda_logit[task]));
    out[q] = lam * s + (1.f - lam) * sp;
  }
}

extern "C" void kernel_launch(void* const* d_in, const int* in_sizes, int n_in,
                              void* d_out, int out_size, void* d_ws, size_t ws_size,
                              hipStream_t stream) {
  const int*   node_ids   = (const int*)d_in[0];
  const int*   edge_index = (const int*)d_in[1];
  const int*   edge_type  = (const int*)d_in[2];
  const int*   heads      = (const int*)d_in[3];
  const int*   rels       = (const int*)d_in[4];
  const int*   tails      = (const int*)d_in[5];
  const float* path_feat  = (const float*)d_in[6];
  const int*   task_idx   = (const int*)d_in[7];
  const float* entity_emb = (const float*)d_in[8];
  const float* rel_emb    = (const float*)d_in[9];
  const float* W_self     = (const float*)d_in[10];
  const float* W_rel      = (const float*)d_in[11];
  const float* delta_w    = (const float*)d_in[12];
  const float* lambda_lg  = (const float*)d_in[13];
  const float* rule_init  = (const float*)d_in[14];

  char* ws = (char*)d_ws;
  size_t off = 0;
  auto alloc = [&](size_t bytes) -> void* {
    void* p = ws + off;
    off = (off + bytes + 255) & ~(size_t)255;
    return p;
  };
  unsigned* h_a    = (unsigned*)alloc((size_t)N_NODES * DIM * 2);
  unsigned* h_b    = (unsigned*)alloc((size_t)N_NODES * DIM * 2);
  short*    wt     = (short*)alloc((size_t)2 * NG * 8 * 512 * 2);
  int*      offs   = (int*)alloc((size_t)(NK + 1) * 4);
  int*      ssrc   = (int*)alloc((size_t)E_EDGES * 4);
  int*      hist   = (int*)alloc((size_t)(NK + 1) * 4);
  int*      cursor = (int*)alloc((size_t)NK * 4);
  int*      bsum   = (int*)alloc((size_t)NBLK_SEG * 4);

  hipMemsetAsync(hist, 0, (size_t)(NK + 1) * 4, stream);
  k_prep<<<EB + H0B + WCB, 256, 0, stream>>>(edge_index, edge_type, hist,
                                             node_ids, entity_emb, h_a,
                                             W_rel, W_self, wt);
  k_bsum<<<NBLK_SEG, 256, 0, stream>>>(hist, bsum);
  k_offsets<<<NBLK_SEG, 256, 0, stream>>>(hist, bsum, offs, cursor);
  k_scatter<<<EB, 256, 0, stream>>>(edge_index, edge_type, cursor, ssrc);

  const unsigned* hin = h_a;
  unsigned* hout = h_b;
  int nblk = (N_NODES + BM - 1) / BM;
  for (int l = 0; l < 2; l++) {
    k_layer<<<nblk, 512, 0, stream>>>(hin, offs, ssrc,
                                      wt + (size_t)l * NG * 8 * 512, hout);
    const unsigned* tmp = hout;
    hout = (unsigned*)hin;
    hin = tmp;
  }
  k_score<<<NQ / 4, 256, 0, stream>>>(hin, heads, rels, tails, rel_emb, path_feat,
                                      task_idx, delta_w, lambda_lg, rule_init,
                                      (float*)d_out);
}

// Round 17
// 420.716 us; speedup vs baseline: 1.2553x; 1.0417x over previous
//
#include <hip/hip_runtime.h>

#define N_NODES 50000
#define N_ENT   100000
#define N_REL   16
#define DIM     128
#define E_EDGES 600000
#define NQ      8192
#define PATH_DIM 5
#define NK      (N_NODES * N_REL)        /* 800000 (rel,dst) segments, rel-major */
#define NBLK_SEG (NK / 256)              /* 3125 */
#define KTOT    (N_REL * DIM + DIM)      /* 2176 */
#define NG      (KTOT / 32)              /* 68 */
#define BM      64                       /* rows per block */
#define EB      ((E_EDGES + 255) / 256)  /* 2344 */
#define H0B     ((N_NODES * 32) / 256)   /* 6250 */
#define WCB     ((2 * NG * 8 * 512) / 256) /* 2176 */

typedef __attribute__((ext_vector_type(8))) short short8;
typedef __attribute__((ext_vector_type(4))) float floatx4;

static __device__ __forceinline__ short f2bf(float x) {
  unsigned u = __builtin_bit_cast(unsigned, x);
  u = (u + 0x7FFFu + ((u >> 16) & 1u)) >> 16;   // RNE
  return (short)u;
}
static __device__ __forceinline__ float bf_lo(unsigned u) {
  return __builtin_bit_cast(float, u << 16);
}
static __device__ __forceinline__ float bf_hi(unsigned u) {
  return __builtin_bit_cast(float, u & 0xffff0000u);
}
static __device__ __forceinline__ unsigned pk2(float a, float b) {
  return (unsigned)(unsigned short)f2bf(a) | ((unsigned)(unsigned short)f2bf(b) << 16);
}

static __device__ __forceinline__ int wave_incl_scan(int x) {
  int lane = threadIdx.x & 63;
  #pragma unroll
  for (int off = 1; off < 64; off <<= 1) {
    int y = __shfl_up(x, off, 64);
    if (lane >= off) x += y;
  }
  return x;
}

// counted-vmcnt primitives (round-9 verified): asm volatile pins program order;
// saddr form keeps address math scalar (SGPR base + shared VGPR byte offset).
static __device__ __forceinline__ unsigned gload_su(const unsigned* base, unsigned voff) {
  unsigned r;
  asm volatile("global_load_dword %0, %1, %2" : "=v"(r) : "v"(voff), "s"(base) : "memory");
  return r;
}
#define WAIT_VM0() do { asm volatile("s_waitcnt vmcnt(0)" ::: "memory"); \
                        __builtin_amdgcn_sched_barrier(0); } while (0)
// raw barrier: does NOT drain vmcnt (round-8 lesson). LDS visibility via lgkmcnt.
#define BAR_LDS() do { asm volatile("s_waitcnt lgkmcnt(0)" ::: "memory"); \
                       __builtin_amdgcn_s_barrier(); \
                       asm volatile("" ::: "memory"); } while (0)

// ---------- fused prep: edge hist | h0 gather | weight tiles ----------
__global__ void k_prep(const int* __restrict__ ei, const int* __restrict__ et,
                       int* __restrict__ hist,
                       const int* __restrict__ nid, const float* __restrict__ emb,
                       unsigned* __restrict__ h,
                       const float* __restrict__ wrel, const float* __restrict__ wself,
                       short* __restrict__ wt) {
  int b = blockIdx.x, t = threadIdx.x;
  if (b < EB) {
    int e = b * 256 + t;
    if (e < E_EDGES) {
      int key = et[e] * N_NODES + ei[E_EDGES + e];
      atomicAdd(&hist[key], 1);
    }
  } else if (b < EB + H0B) {
    int g = (b - EB) * 256 + t;                    // over N*32
    int n = g >> 5, q = g & 31;
    float4 v = *(const float4*)(emb + (size_t)nid[n] * DIM + q * 4);
    uint2 pk;
    pk.x = pk2(v.x, v.y);
    pk.y = pk2(v.z, v.w);
    *(uint2*)(h + (size_t)n * 64 + q * 2) = pk;
  } else {
    // wt layout: [l][g=k/32][nt8=n/16] tile [16 rA][32 q] shorts (1KB).
    // Lane varies rA (=n) fastest -> coalesced wrel/wself reads (round-14 verified).
    int idx = (b - EB - H0B) * 256 + t;
    int u = idx & 511;
    int tile = idx >> 9;
    int rA = u & 15, q = u >> 4;
    int nt8 = tile & 7;
    int lg = tile >> 3;
    int l = lg / NG, g = lg % NG;
    int n = nt8 * 16 + rA;
    int k = g * 32 + q;
    float v;
    if (k < N_REL * DIM) {
      int r = k >> 7, d = k & 127;
      v = wrel[(((size_t)l * N_REL + r) * DIM + d) * DIM + n];
    } else {
      int d = k - N_REL * DIM;
      v = wself[((size_t)l * DIM + d) * DIM + n];
    }
    wt[(size_t)tile * 512 + rA * 32 + q] = f2bf(v);
  }
}

__global__ void k_bsum(const int* __restrict__ hist, int* __restrict__ bsum) {
  int t = threadIdx.x;
  int v = hist[blockIdx.x * 256 + t];
  #pragma unroll
  for (int off = 32; off; off >>= 1) v += __shfl_xor(v, off, 64);
  __shared__ int s4[4];
  if ((t & 63) == 0) s4[t >> 6] = v;
  __syncthreads();
  if (t == 0) bsum[blockIdx.x] = s4[0] + s4[1] + s4[2] + s4[3];
}

// k_offsets computes its own block prefix over bsum (round-14 verified; kills
// the serial 1-block k_bscan dispatch). 3125 L2-hot ints, <=13 reads/thread.
__global__ void k_offsets(const int* __restrict__ hist, const int* __restrict__ bsum,
                          int* __restrict__ offs, int* __restrict__ cursor) {
  int t = threadIdx.x;
  int b = blockIdx.x;
  int g = b * 256 + t;
  int part = 0;
  for (int i = t; i < b; i += 256) part += bsum[i];
  #pragma unroll
  for (int off = 32; off; off >>= 1) part += __shfl_xor(part, off, 64);
  __shared__ int pre4[4];
  int wid = t >> 6, lane = t & 63;
  if (lane == 0) pre4[wid] = part;
  __syncthreads();
  int blockpre = pre4[0] + pre4[1] + pre4[2] + pre4[3];

  int v = hist[g];
  int incl = wave_incl_scan(v);
  __shared__ int wsum[4];
  if (lane == 63) wsum[wid] = incl;
  __syncthreads();
  int wexcl = 0;
  for (int i = 0; i < wid; i++) wexcl += wsum[i];
  int off = blockpre + wexcl + incl - v;
  offs[g] = off;
  cursor[g] = off;
  if (g == NK - 1) offs[NK] = off + v;
}

__global__ void k_scatter(const int* __restrict__ ei, const int* __restrict__ et,
                          int* __restrict__ cursor, int* __restrict__ ssrc) {
  int e = blockIdx.x * 256 + threadIdx.x;
  if (e >= E_EDGES) return;
  int src = ei[e];
  int key = et[e] * N_NODES + ei[E_EDGES + e];
  int pos = atomicAdd(&cursor[key], 1);
  ssrc[pos] = src;
}

// ---------- fused layer (round-9 structure + chunked exact-issue) ----------
// 4 producer waves (16 segs each) + 4 consumer waves. Raw s_barrier (no vmcnt
// drain) spans the pipeline across phases. Issue counts are now VARIABLE
// (4 wave-uniform chunks of 8, guarded by the real segment-range size), so
// waits use vmcnt(0) at phase top -- the waited loads were issued one full
// phase earlier (same depth as the old counted scheme, count-agnostic).
__global__ __launch_bounds__(512, 4)
void k_layer(const unsigned* __restrict__ hin, const int* __restrict__ offs,
             const int* __restrict__ ssrc, const short* __restrict__ wt,
             unsigned* __restrict__ hout) {
  __shared__ unsigned As[2][BM][68];  // 272B row stride, double-buffered
  __shared__ int offsS[16][66];       // per-rel segment boundaries for block rows
  int t = threadIdx.x;
  int w = t >> 6, lane = t & 63;
  int row0 = blockIdx.x * BM;

  for (int idx = t; idx < 16 * 80; idx += 512) {
    int it = idx / 80, rr = idx - it * 80;
    if (rr < 65) offsS[it][rr] = offs[min(it * N_NODES + row0 + rr, NK)];
  }
  BAR_LDS();                          // barrier #0

  if (w < 4) {
    // ================= producer =================
    int w16 = w * 16;
    unsigned voffl = (unsigned)lane * 4u;   // shared per-lane byte offset
    unsigned uA[32], uB[32];
    int sjA, sjB;

    auto totr = [&](int r) -> int {         // wave-uniform range size of rel r
      return offsS[r][w16 + 16] - offsS[r][w16];
    };
    auto issue_sj = [&](int r) -> int {     // 64 edge ids of this wave's range
      int o0 = offsS[r][w16];
      unsigned vo = (unsigned)min(o0 + lane, E_EDGES - 1) * 4u;
      return (int)gload_su((const unsigned*)ssrc, vo);
    };
    // chunked exact-issue: only ceil(tot/8)*8 row loads (uniform SALU guards)
    auto issue_u = [&](unsigned (&u)[32], int sjv, int tot) {
      #pragma unroll
      for (int ch = 0; ch < 4; ++ch) {
        if (tot > ch * 8) {
          #pragma unroll
          for (int e2 = 0; e2 < 8; ++e2) {
            int e = ch * 8 + e2;
            int sr = __builtin_amdgcn_readlane(sjv, e);
            u[e] = gload_su(hin + (size_t)sr * 64, voffl);
          }
        }
      }
    };
    auto accum = [&](unsigned (&u)[32], int r) {
      int olv = offsS[r][w16 + min(lane, 16)];
      int o0 = __builtin_amdgcn_readfirstlane(olv);
      int total = __builtin_amdgcn_readlane(olv, 16) - o0;
      int nxt = __shfl(olv, lane + 1);
      int cnl = nxt - olv;                            // lanes 0..15 meaningful
      float ivf = 1.0f / (float)(cnl > 0 ? cnl : 1);  // one div per wave-rel
      int ivb = __builtin_bit_cast(int, ivf);
      int k = 0;
      int nb = __builtin_amdgcn_readlane(olv, 1) - o0;
      float r0 = 0.f, r1 = 0.f;
      int buf = r & 1;
      auto close1 = [&]() {
        float f = __builtin_bit_cast(float, __builtin_amdgcn_readlane(ivb, k));
        float a = r0 * f, b2 = r1 * f;
        unsigned pk;
        asm("v_cvt_pk_bf16_f32 %0, %1, %2" : "=v"(pk) : "v"(a), "v"(b2));  // RNE
        As[buf][w16 + k][lane] = pk;
        r0 = 0.f; r1 = 0.f;
        ++k;
        nb = __builtin_amdgcn_readlane(olv, min(k + 1, 16)) - o0;
      };
      #pragma unroll
      for (int e = 0; e < 32; ++e) {
        while (k < 16 && nb == e) close1();           // segs ending at pos e (incl empties)
        if (e < total) { r0 += bf_lo(u[e]); r1 += bf_hi(u[e]); }
      }
      if (total > 32) {                               // rare serial tail (drains pipe; self-heals)
        for (int e = 32; e < total; ++e) {
          while (k < 16 && nb == e) close1();
          int sr = __builtin_amdgcn_readfirstlane(ssrc[o0 + e]);
          unsigned uu = hin[(size_t)sr * 64 + lane];
          r0 += bf_lo(uu); r1 += bf_hi(uu);
        }
      }
      while (k < 16) close1();                        // segs ending at total + trailing empties
    };

    // ---- prologue ----
    sjA = issue_sj(0);
    WAIT_VM0();                        // sjA ready
    sjB = issue_sj(1);
    issue_u(uA, sjA, totr(0));         // rel 0 rows in flight
    WAIT_VM0();                        // uA + sjB ready
    sjA = issue_sj(2);
    issue_u(uB, sjB, totr(1));         // rel 1 rows in flight
    accum(uA, 0);
    BAR_LDS();                         // barrier #1: As[0] visible

    // ---- phases p = 0..14 (produce rels 1..15) ----
    // entry invariant: outstanding = u(p+1) rows + sj(p+2), issued a phase ago
    auto phase = [&](int p, unsigned (&uI)[32], unsigned (&uAcc)[32],
                     int &sjC, int &sjN) {
      WAIT_VM0();                      // u(p+1) + sj(p+2) ready
      if (p + 3 <= 15) sjN = issue_sj(p + 3);
      if (p + 2 <= 15) issue_u(uI, sjC, totr(p + 2));
      accum(uAcc, p + 1);
      BAR_LDS();
    };
    for (int p = 0; p < 15; p += 2) {
      phase(p, uA, uB, sjA, sjB);
      if (p + 1 < 15) phase(p + 1, uB, uA, sjB, sjA);
    }

    // ---- self slot into As[0] (consumed at it=16) ----
    #pragma unroll
    for (int j = 0; j < 16; ++j) {
      int lr = min(row0 + w16 + j, N_NODES - 1);
      As[0][w16 + j][lane] = hin[(size_t)lr * 64 + lane];
    }
    BAR_LDS();                         // barrier #17
  } else {
    // ================= consumer =================
    int wid = w - 4, wm = wid >> 1, wn = wid & 1;
    int quad = lane >> 4, rA = lane & 15;
    floatx4 acc[2][4];
    #pragma unroll
    for (int a = 0; a < 2; a++)
      #pragma unroll
      for (int b = 0; b < 4; b++) acc[a][b] = (floatx4)0.f;

    BAR_LDS();                         // barrier #1 (matches producer prologue)
    for (int it = 0; it < 17; ++it) {
      int buf = it & 1;
      const short* arow0 = (const short*)&As[buf][wm * 32 + rA][0];
      const short* arow1 = (const short*)&As[buf][wm * 32 + 16 + rA][0];
      #pragma unroll
      for (int ks = 0; ks < 4; ++ks) {
        short8 a0 = *(const short8*)(arow0 + ks * 32 + quad * 8);
        short8 a1 = *(const short8*)(arow1 + ks * 32 + quad * 8);
        int kg = it * 4 + ks;
        const short* bp = wt + (size_t)(kg * 8 + wn * 4) * 512 + rA * 32 + quad * 8;
        #pragma unroll
        for (int nt = 0; nt < 4; ++nt) {
          short8 b = *(const short8*)(bp + nt * 512);  // 1KB tile, L2-hot
          acc[0][nt] = __builtin_amdgcn_mfma_f32_16x16x32_bf16(a0, b, acc[0][nt], 0, 0, 0);
          acc[1][nt] = __builtin_amdgcn_mfma_f32_16x16x32_bf16(a1, b, acc[1][nt], 0, 0, 0);
        }
      }
      if (it < 16) BAR_LDS();          // barriers #2..#17
    }
    // epilogue: C row=(lane>>4)*4+j, col=lane&15 within each 16x16 tile
    #pragma unroll
    for (int mt = 0; mt < 2; ++mt)
      #pragma unroll
      for (int nt = 0; nt < 4; ++nt)
        #pragma unroll
        for (int j = 0; j < 4; ++j) {
          int row = row0 + wm * 32 + mt * 16 + quad * 4 + j;
          int col = wn * 64 + nt * 16 + rA;
          if (row < N_NODES)
            ((short*)hout)[(size_t)row * DIM + col] = f2bf(fmaxf(acc[mt][nt][j], 0.f));
        }
  }
}

// ---------- scoring (bf16 h) ----------
__global__ void k_score(const unsigned* __restrict__ h, const int* __restrict__ heads,
                        const int* __restrict__ rels, const int* __restrict__ tails,
                        const float* __restrict__ rel_emb, const float* __restrict__ path_feat,
                        const int* __restrict__ task_idx, const float* __restrict__ delta_w,
                        const float* __restrict__ lambda_logit, const float* __restrict__ rule_init,
                        float* __restrict__ out) {
  int q = (blockIdx.x * 256 + threadIdx.x) >> 6;
  int lane = threadIdx.x & 63;
  int hd = heads[q], tl = tails[q], rl = rels[q];
  unsigned ua = h[(size_t)hd * 64 + lane];
  unsigned uc = h[(size_t)tl * 64 + lane];
  float2 r = *(const float2*)(rel_emb + (size_t)rl * DIM + lane * 2);
  float s = bf_lo(ua) * r.x * bf_lo(uc) + bf_hi(ua) * r.y * bf_hi(uc);
  #pragma unroll
  for (int off = 32; off; off >>= 1) s += __shfl_xor(s, off, 64);
  if (lane == 0) {
    int task = task_idx[0];
    float sp = 0.f;
    #pragma unroll
    for (int p = 0; p < PATH_DIM; p++)
      sp += path_feat[q * PATH_DIM + p] *
            (rule_init[task * PATH_DIM + p] + delta_w[task * PATH_DIM + p]);
    float lam = 1.f / (1.f + __expf(-lambda_logit[task]));
    out[q] = lam * s + (1.f - lam) * sp;
  }
}

extern "C" void kernel_launch(void* const* d_in, const int* in_sizes, int n_in,
                              void* d_out, int out_size, void* d_ws, size_t ws_size,
                              hipStream_t stream) {
  const int*   node_ids   = (const int*)d_in[0];
  const int*   edge_index = (const int*)d_in[1];
  const int*   edge_type  = (const int*)d_in[2];
  const int*   heads      = (const int*)d_in[3];
  const int*   rels       = (const int*)d_in[4];
  const int*   tails      = (const int*)d_in[5];
  const float* path_feat  = (const float*)d_in[6];
  const int*   task_idx   = (const int*)d_in[7];
  const float* entity_emb = (const float*)d_in[8];
  const float* rel_emb    = (const float*)d_in[9];
  const float* W_self     = (const float*)d_in[10];
  const float* W_rel      = (const float*)d_in[11];
  const float* delta_w    = (const float*)d_in[12];
  const float* lambda_lg  = (const float*)d_in[13];
  const float* rule_init  = (const float*)d_in[14];

  char* ws = (char*)d_ws;
  size_t off = 0;
  auto alloc = [&](size_t bytes) -> void* {
    void* p = ws + off;
    off = (off + bytes + 255) & ~(size_t)255;
    return p;
  };
  unsigned* h_a    = (unsigned*)alloc((size_t)N_NODES * DIM * 2);
  unsigned* h_b    = (unsigned*)alloc((size_t)N_NODES * DIM * 2);
  short*    wt     = (short*)alloc((size_t)2 * NG * 8 * 512 * 2);
  int*      offs   = (int*)alloc((size_t)(NK + 1) * 4);
  int*      ssrc   = (int*)alloc((size_t)E_EDGES * 4);
  int*      hist   = (int*)alloc((size_t)(NK + 1) * 4);
  int*      cursor = (int*)alloc((size_t)NK * 4);
  int*      bsum   = (int*)alloc((size_t)NBLK_SEG * 4);

  hipMemsetAsync(hist, 0, (size_t)(NK + 1) * 4, stream);
  k_prep<<<EB + H0B + WCB, 256, 0, stream>>>(edge_index, edge_type, hist,
                                             node_ids, entity_emb, h_a,
                                             W_rel, W_self, wt);
  k_bsum<<<NBLK_SEG, 256, 0, stream>>>(hist, bsum);
  k_offsets<<<NBLK_SEG, 256, 0, stream>>>(hist, bsum, offs, cursor);
  k_scatter<<<EB, 256, 0, stream>>>(edge_index, edge_type, cursor, ssrc);

  const unsigned* hin = h_a;
  unsigned* hout = h_b;
  int nblk = (N_NODES + BM - 1) / BM;
  for (int l = 0; l < 2; l++) {
    k_layer<<<nblk, 512, 0, stream>>>(hin, offs, ssrc,
                                      wt + (size_t)l * NG * 8 * 512, hout);
    const unsigned* tmp = hout;
    hout = (unsigned*)hin;
    hin = tmp;
  }
  k_score<<<NQ / 4, 256, 0, stream>>>(hin, heads, rels, tails, rel_emb, path_feat,
                                      task_idx, delta_w, lambda_lg, rule_init,
                                      (float*)d_out);
}